// Round 2
// baseline (1365.371 us; speedup 1.0000x reference)
//
#include <hip/hip_runtime.h>
#include <math.h>

// Markowitz min-variance via FISTA, one block (512 thr, 8 waves) per problem.
// Q register-resident: thread (r4=tid&63, e=tid>>6) owns Q[4*r4..+3][32*e..+31].
// R4: ALL-WAVE REDUNDANT projection. Every wave computes the reduce + capped-
// simplex projection + FISTA update in lockstep (identical fp32 ops -> identical
// results, zero barrier skew). y lives in registers; the matvec broadcasts it
// wave-locally via v_readlane (uniform lane index). Partial exchange is the only
// inter-wave traffic: double-buffered p_lds -> ONE __syncthreads per iteration.
// Newton tolerance 1e-5, exact-tau folded into final Newton eval, frozen-w
// early exit as a uniform register-computed break (no LDS flag).
// (R4 resubmit: previous bench attempt died to container-acquire failure.)

#define NA    256
#define CAPW  0.05f

typedef float v2f __attribute__((ext_vector_type(2)));

// ---- DPP wave-64 reductions ----
template<int CTRL, int RM>
__device__ __forceinline__ float dpp0(float x) {      // old = 0, bound_ctrl = true
    return __int_as_float(__builtin_amdgcn_update_dpp(
        0, __float_as_int(x), CTRL, RM, 0xf, true));
}
template<int CTRL, int RM>
__device__ __forceinline__ float dppI(float x, float ident) { // old = ident
    return __int_as_float(__builtin_amdgcn_update_dpp(
        __float_as_int(ident), __float_as_int(x), CTRL, RM, 0xf, false));
}
__device__ __forceinline__ float bcast63(float x) {
    return __int_as_float(__builtin_amdgcn_readlane(__float_as_int(x), 63));
}
__device__ __forceinline__ float rlane(float x, int lane) {
    return __int_as_float(__builtin_amdgcn_readlane(__float_as_int(x), lane));
}
__device__ __forceinline__ float wsum(float x) {
    x += dpp0<0x111, 0xf>(x);   // row_shr:1
    x += dpp0<0x112, 0xf>(x);   // row_shr:2
    x += dpp0<0x114, 0xf>(x);   // row_shr:4
    x += dpp0<0x118, 0xf>(x);   // row_shr:8
    x += dpp0<0x142, 0xa>(x);   // row_bcast:15 -> rows 1,3
    x += dpp0<0x143, 0xc>(x);   // row_bcast:31 -> rows 2,3
    return bcast63(x);
}
__device__ __forceinline__ float wmin(float x) {
    const float I = 1e30f;
    x = fminf(x, dppI<0x111, 0xf>(x, I));
    x = fminf(x, dppI<0x112, 0xf>(x, I));
    x = fminf(x, dppI<0x114, 0xf>(x, I));
    x = fminf(x, dppI<0x118, 0xf>(x, I));
    x = fminf(x, dppI<0x142, 0xa>(x, I));
    x = fminf(x, dppI<0x143, 0xc>(x, I));
    return bcast63(x);
}
__device__ __forceinline__ float wmax(float x) {
    const float I = -1e30f;
    x = fmaxf(x, dppI<0x111, 0xf>(x, I));
    x = fmaxf(x, dppI<0x112, 0xf>(x, I));
    x = fmaxf(x, dppI<0x114, 0xf>(x, I));
    x = fmaxf(x, dppI<0x118, 0xf>(x, I));
    x = fmaxf(x, dppI<0x142, 0xa>(x, I));
    x = fmaxf(x, dppI<0x143, 0xc>(x, I));
    return bcast63(x);
}

__global__ void __launch_bounds__(512, 2)
markowitz_fista(const float* __restrict__ A, float* __restrict__ out)
{
    __shared__ float A_lds[32 * 256];       // build-phase A staging (32 KB)
    __shared__ float p_lds[2][8 * 256];     // double-buffered matvec partials (16 KB)

    const int tid = threadIdx.x;
    const int b   = blockIdx.x;
    const int r4  = tid & 63;
    const int e   = tid >> 6;               // wave id == col-chunk
    const int R0  = r4 * 4;
    const int C0  = e * 32;
    // uniform lane base for wave-local y broadcast: y[4L..4L+3] lives in lane L;
    // wave e's columns 32e..32e+31 live in lanes 8e..8e+7 (of every wave).
    const int lb  = __builtin_amdgcn_readfirstlane(e) * 8;

    const float* __restrict__ Ab = A + (size_t)b * NA * NA;

    // ---------------- Phase 1: Q = A^T A into registers (packed fp32) -------
    v2f q2[4][16];
    #pragma unroll
    for (int a = 0; a < 4; ++a)
        #pragma unroll
        for (int k = 0; k < 16; ++k) q2[a][k] = (v2f){0.0f, 0.0f};

    for (int it = 0; it < 8; ++it) {
        __syncthreads();
        const float4* src = (const float4*)(Ab + it * 32 * 256);
        float4* dst = (float4*)A_lds;
        #pragma unroll
        for (int qd = 0; qd < 4; ++qd) dst[qd * 512 + tid] = src[qd * 512 + tid];
        __syncthreads();
        for (int ii = 0; ii < 32; ++ii) {
            const float* row = A_lds + ii * 256;
            float4 rv = *(const float4*)(row + R0);
            v2f r0 = {rv.x, rv.x}, r1 = {rv.y, rv.y}, r2 = {rv.z, rv.z}, r3 = {rv.w, rv.w};
            #pragma unroll
            for (int cc = 0; cc < 8; ++cc) {
                float4 cv = *(const float4*)(row + C0 + 4 * cc);
                v2f clo = {cv.x, cv.y}, chi = {cv.z, cv.w};
                q2[0][2*cc  ] = __builtin_elementwise_fma(r0, clo, q2[0][2*cc  ]);
                q2[0][2*cc+1] = __builtin_elementwise_fma(r0, chi, q2[0][2*cc+1]);
                q2[1][2*cc  ] = __builtin_elementwise_fma(r1, clo, q2[1][2*cc  ]);
                q2[1][2*cc+1] = __builtin_elementwise_fma(r1, chi, q2[1][2*cc+1]);
                q2[2][2*cc  ] = __builtin_elementwise_fma(r2, clo, q2[2][2*cc  ]);
                q2[2][2*cc+1] = __builtin_elementwise_fma(r2, chi, q2[2][2*cc+1]);
                q2[3][2*cc  ] = __builtin_elementwise_fma(r3, clo, q2[3][2*cc  ]);
                q2[3][2*cc+1] = __builtin_elementwise_fma(r3, chi, q2[3][2*cc+1]);
            }
        }
    }

    // matvec partials from REGISTER y (every lane of every wave holds y[4*r4..+3]).
    // Wave e broadcasts y[32e+4cc+j] = lane (8e+cc)'s register j via v_readlane.
    auto matvec = [&](float y0, float y1, float y2, float y3, float* buf) {
        v2f aL0 = {0,0}, aL1 = {0,0}, aL2 = {0,0}, aL3 = {0,0};
        v2f aH0 = {0,0}, aH1 = {0,0}, aH2 = {0,0}, aH3 = {0,0};
        #pragma unroll
        for (int cc = 0; cc < 8; ++cc) {
            const int L = lb + cc;                 // wave-uniform lane index
            v2f ylo = { rlane(y0, L), rlane(y1, L) };
            v2f yhi = { rlane(y2, L), rlane(y3, L) };
            aL0 = __builtin_elementwise_fma(q2[0][2*cc  ], ylo, aL0);
            aH0 = __builtin_elementwise_fma(q2[0][2*cc+1], yhi, aH0);
            aL1 = __builtin_elementwise_fma(q2[1][2*cc  ], ylo, aL1);
            aH1 = __builtin_elementwise_fma(q2[1][2*cc+1], yhi, aH1);
            aL2 = __builtin_elementwise_fma(q2[2][2*cc  ], ylo, aL2);
            aH2 = __builtin_elementwise_fma(q2[2][2*cc+1], yhi, aH2);
            aL3 = __builtin_elementwise_fma(q2[3][2*cc  ], ylo, aL3);
            aH3 = __builtin_elementwise_fma(q2[3][2*cc+1], yhi, aH3);
        }
        v2f s0 = aL0 + aH0, s1 = aL1 + aH1, s2 = aL2 + aH2, s3 = aL3 + aH3;
        *(float4*)(buf + e * 256 + R0) =
            make_float4(s0.x + s0.y, s1.x + s1.y, s2.x + s2.y, s3.x + s3.y);
    };
    // every wave reduces the 8 partials for rows 4*r4..4*r4+3 (redundant)
    auto reduceg = [&](const float* buf) -> float4 {
        float4 r = *(const float4*)(buf + R0);
        #pragma unroll
        for (int ee = 1; ee < 8; ++ee) {
            float4 pv = *(const float4*)(buf + ee * 256 + R0);
            r.x += pv.x; r.y += pv.y; r.z += pv.z; r.w += pv.w;
        }
        return r;
    };

    // ---------------- Phase 2: power iteration for step size ----------------
    float u0 = 0.0625f, u1 = 0.0625f, u2 = 0.0625f, u3 = 0.0625f;
    matvec(u0, u1, u2, u3, p_lds[0]);
    __syncthreads();
    int pb = 0;
    for (int p = 0; p < 30; ++p) {
        float4 g4 = reduceg(p_lds[pb]);
        float ss = wsum(g4.x*g4.x + g4.y*g4.y + g4.z*g4.z + g4.w*g4.w);
        float inv = 1.0f / (sqrtf(ss) + 1e-12f);
        u0 = g4.x * inv; u1 = g4.y * inv; u2 = g4.z * inv; u3 = g4.w * inv;
        pb ^= 1;
        matvec(u0, u1, u2, u3, p_lds[pb]);
        __syncthreads();
    }
    // Rayleigh quotient with Q*u_30
    float4 gq = reduceg(p_lds[pb]);
    float lm = wsum(u0*gq.x + u1*gq.y + u2*gq.z + u3*gq.w);
    float step  = 1.0f / (2.0f * lm + 1e-12f);
    float step2 = 2.0f * step;

    float t = 1.0f, tau_ws = 0.0f, rm = 0.0f;
    float wa = 1.0f/256.0f, wb = 1.0f/256.0f, wc = 1.0f/256.0f, wd = 1.0f/256.0f;
    float ya = wa, yb = wb, yc = wc, yd = wd;   // project(uniform) = uniform (tau=0)

    // prime FISTA matvec
    pb ^= 1;
    matvec(ya, yb, yc, yd, p_lds[pb]);
    __syncthreads();

    // ---------------- Phase 3: FISTA (all waves in lockstep) ----------------
    for (int itn = 0; itn < 300; ++itn) {
        float4 g4 = reduceg(p_lds[pb]);
        float v0 = ya - step2 * g4.x;
        float v1 = yb - step2 * g4.y;
        float v2 = yc - step2 * g4.z;
        float v3 = yd - step2 * g4.w;

        float lo = wmin(fminf(fminf(v0, v1), fminf(v2, v3))) - CAPW;
        float hi = wmax(fmaxf(fmaxf(v0, v1), fmaxf(v2, v3))) + CAPW;
        float tau = fminf(fmaxf(tau_ws, lo), hi);

        float s = 0.f, cnt = 1.f, sm1 = 0.f;
        bool have = false;
        for (int ni = 0; ni < 10; ++ni) {
            float z0 = v0 - tau, z1 = v1 - tau, z2 = v2 - tau, z3 = v3 - tau;
            float c0 = fminf(fmaxf(z0, -CAPW), CAPW);
            float c1 = fminf(fmaxf(z1, -CAPW), CAPW);
            float c2 = fminf(fmaxf(z2, -CAPW), CAPW);
            float c3 = fminf(fmaxf(z3, -CAPW), CAPW);
            s   = wsum(c0 + c1 + c2 + c3);
            cnt = wsum((fabsf(z0) < CAPW ? 1.f : 0.f) +
                       (fabsf(z1) < CAPW ? 1.f : 0.f) +
                       (fabsf(z2) < CAPW ? 1.f : 0.f) +
                       (fabsf(z3) < CAPW ? 1.f : 0.f));
            sm1 = s - 1.0f;
            if (fabsf(sm1) <= 1e-5f) { have = true; break; }   // wave-uniform
            if (sm1 > 0.0f) lo = tau; else hi = tau;
            float tn2 = tau + sm1 / fmaxf(cnt, 1.0f);   // Newton: s' = -n_int
            if (!(tn2 > lo && tn2 < hi)) tn2 = 0.5f * (lo + hi);
            tau = tn2;
        }
        if (!have) {   // bound-exit: re-eval (s,cnt) at final tau
            float z0 = v0 - tau, z1 = v1 - tau, z2 = v2 - tau, z3 = v3 - tau;
            float c0 = fminf(fmaxf(z0, -CAPW), CAPW);
            float c1 = fminf(fmaxf(z1, -CAPW), CAPW);
            float c2 = fminf(fmaxf(z2, -CAPW), CAPW);
            float c3 = fminf(fmaxf(z3, -CAPW), CAPW);
            s   = wsum(c0 + c1 + c2 + c3);
            cnt = wsum((fabsf(z0) < CAPW ? 1.f : 0.f) +
                       (fabsf(z1) < CAPW ? 1.f : 0.f) +
                       (fabsf(z2) < CAPW ? 1.f : 0.f) +
                       (fabsf(z3) < CAPW ? 1.f : 0.f));
            sm1 = s - 1.0f;
        }
        // exact active-set tau == one Newton step from converged point
        float tauf = tau + sm1 / fmaxf(cnt, 1.0f);
        tau_ws = tauf;
        float w0n = fminf(fmaxf(v0 - tauf, -CAPW), CAPW);
        float w1n = fminf(fmaxf(v1 - tauf, -CAPW), CAPW);
        float w2n = fminf(fmaxf(v2 - tauf, -CAPW), CAPW);
        float w3n = fminf(fmaxf(v3 - tauf, -CAPW), CAPW);

        float tn = 0.5f * (1.0f + sqrtf(1.0f + 4.0f * t * t));
        float beta = (t - 1.0f) / tn;
        float y0n = w0n + beta * (w0n - wa);
        float y1n = w1n + beta * (w1n - wb);
        float y2n = w2n + beta * (w2n - wc);
        float y3n = w3n + beta * (w3n - wd);

        // frozen-w detection (8-iter window); identical in every wave -> uniform break
        float dm = fmaxf(fmaxf(fabsf(w0n - wa), fabsf(w1n - wb)),
                         fmaxf(fabsf(w2n - wc), fabsf(w3n - wd)));
        rm = fmaxf(rm, dm);
        bool stop = false;
        if ((itn & 7) == 7) {
            float rmax = wmax(rm);
            stop = (rmax < 1e-10f);
            rm = 0.0f;
        }

        wa = w0n; wb = w1n; wc = w2n; wd = w3n;
        ya = y0n; yb = y1n; yc = y2n; yd = y3n;
        t = tn;

        if (stop || itn == 299) break;     // uniform across all waves

        pb ^= 1;
        matvec(ya, yb, yc, yd, p_lds[pb]);
        __syncthreads();
    }

    if (tid < 64) {
        *(float4*)(out + b * 256 + R0) = make_float4(wa, wb, wc, wd);
    }
}

extern "C" void kernel_launch(void* const* d_in, const int* in_sizes, int n_in,
                              void* d_out, int out_size, void* d_ws, size_t ws_size,
                              hipStream_t stream) {
    (void)in_sizes; (void)n_in; (void)d_ws; (void)ws_size; (void)out_size;
    const float* A = (const float*)d_in[0];
    float* out = (float*)d_out;
    hipLaunchKernelGGL(markowitz_fista, dim3(512), dim3(512), 0, stream, A, out);
}

// Round 3
// 904.815 us; speedup vs baseline: 1.5090x; 1.5090x over previous
//
#include <hip/hip_runtime.h>
#include <math.h>

// Markowitz min-variance via FISTA, one block (512 thr, 8 waves) per problem.
// Q register-resident: thread (r4=tid&63, e=tid>>6) owns Q[4*r4..+3][32*e..+31].
// R5: R3 structure (wave0-serial projection — proven 1056us; R4's all-wave
// redundancy was issue-bound at 1 block/CU and regressed). Occupancy is
// structurally 1 block/CU (q2 = 128 VGPR/thread of Q -> ~220 total), so the
// only lever is the serial chain. Changes vs R3:
//  - constant Newton bracket [-2,2] (provably valid: |v|inf <= ~1.5) removes
//    the wmin/wmax DPP chains from the per-iter serial path
//  - Newton tolerance 1e-5 -> 5e-5 (|tau-tau*| <= tol/n_int stays far under a
//    linear-piece width; final exact active-set step unchanged) cuts spin trips
//  - extrapolated warm start tau0 = 2*tau_ws - tau_prev
//  - LDS union: phase-1 A staging reuses the same 32KB pool as p_lds/y_lds
//    (barrier added after phase 1 for alias safety)

#define NA    256
#define CAPW  0.05f

typedef float v2f __attribute__((ext_vector_type(2)));

// ---- DPP wave-64 reductions ----
template<int CTRL, int RM>
__device__ __forceinline__ float dpp0(float x) {      // old = 0, bound_ctrl = true
    return __int_as_float(__builtin_amdgcn_update_dpp(
        0, __float_as_int(x), CTRL, RM, 0xf, true));
}
template<int CTRL, int RM>
__device__ __forceinline__ float dppI(float x, float ident) { // old = ident
    return __int_as_float(__builtin_amdgcn_update_dpp(
        __float_as_int(ident), __float_as_int(x), CTRL, RM, 0xf, false));
}
__device__ __forceinline__ float bcast63(float x) {
    return __int_as_float(__builtin_amdgcn_readlane(__float_as_int(x), 63));
}
__device__ __forceinline__ float wsum(float x) {
    x += dpp0<0x111, 0xf>(x);   // row_shr:1
    x += dpp0<0x112, 0xf>(x);   // row_shr:2
    x += dpp0<0x114, 0xf>(x);   // row_shr:4
    x += dpp0<0x118, 0xf>(x);   // row_shr:8
    x += dpp0<0x142, 0xa>(x);   // row_bcast:15 -> rows 1,3
    x += dpp0<0x143, 0xc>(x);   // row_bcast:31 -> rows 2,3
    return bcast63(x);
}
__device__ __forceinline__ float wmax(float x) {
    const float I = -1e30f;
    x = fmaxf(x, dppI<0x111, 0xf>(x, I));
    x = fmaxf(x, dppI<0x112, 0xf>(x, I));
    x = fmaxf(x, dppI<0x114, 0xf>(x, I));
    x = fmaxf(x, dppI<0x118, 0xf>(x, I));
    x = fmaxf(x, dppI<0x142, 0xa>(x, I));
    x = fmaxf(x, dppI<0x143, 0xc>(x, I));
    return bcast63(x);
}

__global__ void __launch_bounds__(512, 2)
markowitz_fista(const float* __restrict__ A, float* __restrict__ out)
{
    // 32KB pool: phase 1 uses all of it as A staging; afterwards the first
    // 8KB are the matvec partials and the next 1KB is the published y vector.
    __shared__ float lds_pool[32 * 256];
    __shared__ int   done_flag;

    float* A_lds = lds_pool;            // [32*256] during phase 1 only
    float* p_lds = lds_pool;            // [8][256] partials, after phase 1
    float* y_lds = lds_pool + 2048;     // [256] published y, after phase 1

    const int tid = threadIdx.x;
    const int b   = blockIdx.x;
    const int r4  = tid & 63;
    const int e   = tid >> 6;           // wave id == col-chunk
    const int R0  = r4 * 4;
    const int C0  = e * 32;

    const float* __restrict__ Ab = A + (size_t)b * NA * NA;

    // ---------------- Phase 1: Q = A^T A into registers (packed fp32) -------
    v2f q2[4][16];
    #pragma unroll
    for (int a = 0; a < 4; ++a)
        #pragma unroll
        for (int k = 0; k < 16; ++k) q2[a][k] = (v2f){0.0f, 0.0f};

    for (int it = 0; it < 8; ++it) {
        __syncthreads();
        const float4* src = (const float4*)(Ab + it * 32 * 256);
        float4* dst = (float4*)A_lds;
        #pragma unroll
        for (int qd = 0; qd < 4; ++qd) dst[qd * 512 + tid] = src[qd * 512 + tid];
        __syncthreads();
        for (int ii = 0; ii < 32; ++ii) {
            const float* row = A_lds + ii * 256;
            float4 rv = *(const float4*)(row + R0);
            v2f r0 = {rv.x, rv.x}, r1 = {rv.y, rv.y}, r2 = {rv.z, rv.z}, r3 = {rv.w, rv.w};
            #pragma unroll
            for (int cc = 0; cc < 8; ++cc) {
                float4 cv = *(const float4*)(row + C0 + 4 * cc);
                v2f clo = {cv.x, cv.y}, chi = {cv.z, cv.w};
                q2[0][2*cc  ] = __builtin_elementwise_fma(r0, clo, q2[0][2*cc  ]);
                q2[0][2*cc+1] = __builtin_elementwise_fma(r0, chi, q2[0][2*cc+1]);
                q2[1][2*cc  ] = __builtin_elementwise_fma(r1, clo, q2[1][2*cc  ]);
                q2[1][2*cc+1] = __builtin_elementwise_fma(r1, chi, q2[1][2*cc+1]);
                q2[2][2*cc  ] = __builtin_elementwise_fma(r2, clo, q2[2][2*cc  ]);
                q2[2][2*cc+1] = __builtin_elementwise_fma(r2, chi, q2[2][2*cc+1]);
                q2[3][2*cc  ] = __builtin_elementwise_fma(r3, clo, q2[3][2*cc  ]);
                q2[3][2*cc+1] = __builtin_elementwise_fma(r3, chi, q2[3][2*cc+1]);
            }
        }
    }
    __syncthreads();   // alias safety: all A_lds reads done before p/y reuse

    // all waves: partials of Q*y_lds into p_lds.  Returns true on early-exit
    // (flag read is issued first and hidden behind the matvec FMAs).
    auto partials = [&](bool chk) -> bool {
        __syncthreads();                               // B1: y_lds / flag visible
        int fl = chk ? done_flag : 0;
        v2f aL0 = {0,0}, aL1 = {0,0}, aL2 = {0,0}, aL3 = {0,0};
        v2f aH0 = {0,0}, aH1 = {0,0}, aH2 = {0,0}, aH3 = {0,0};
        const float* yv = y_lds + C0;
        #pragma unroll
        for (int cc = 0; cc < 8; ++cc) {
            float4 y4 = *(const float4*)(yv + 4 * cc);
            v2f ylo = {y4.x, y4.y}, yhi = {y4.z, y4.w};
            aL0 = __builtin_elementwise_fma(q2[0][2*cc  ], ylo, aL0);
            aH0 = __builtin_elementwise_fma(q2[0][2*cc+1], yhi, aH0);
            aL1 = __builtin_elementwise_fma(q2[1][2*cc  ], ylo, aL1);
            aH1 = __builtin_elementwise_fma(q2[1][2*cc+1], yhi, aH1);
            aL2 = __builtin_elementwise_fma(q2[2][2*cc  ], ylo, aL2);
            aH2 = __builtin_elementwise_fma(q2[2][2*cc+1], yhi, aH2);
            aL3 = __builtin_elementwise_fma(q2[3][2*cc  ], ylo, aL3);
            aH3 = __builtin_elementwise_fma(q2[3][2*cc+1], yhi, aH3);
        }
        if (fl) return true;                           // block-uniform
        v2f s0 = aL0 + aH0, s1 = aL1 + aH1, s2 = aL2 + aH2, s3 = aL3 + aH3;
        *(float4*)(p_lds + e * 256 + R0) =
            make_float4(s0.x + s0.y, s1.x + s1.y, s2.x + s2.y, s3.x + s3.y);
        __syncthreads();                               // B2: p_lds visible
        return false;
    };
    // wave0 (tid<64): reduce the 8 partials for rows 4*tid..4*tid+3
    auto reduceg = [&]() -> float4 {
        float4 r = *(const float4*)(p_lds + 4 * tid);
        #pragma unroll
        for (int ee = 1; ee < 8; ++ee) {
            float4 pv = *(const float4*)(p_lds + ee * 256 + 4 * tid);
            r.x += pv.x; r.y += pv.y; r.z += pv.z; r.w += pv.w;
        }
        return r;
    };

    // ---------------- Phase 2: power iteration for step size ----------------
    if (tid < 64) {
        *(float4*)(y_lds + 4 * tid) = make_float4(0.0625f, 0.0625f, 0.0625f, 0.0625f);
    }
    float u0 = 0.f, u1 = 0.f, u2 = 0.f, u3 = 0.f;
    for (int p = 0; p < 30; ++p) {
        partials(false);
        if (tid < 64) {
            float4 g4 = reduceg();
            float ss = wsum(g4.x*g4.x + g4.y*g4.y + g4.z*g4.z + g4.w*g4.w);
            float inv = 1.0f / (sqrtf(ss) + 1e-12f);
            u0 = g4.x * inv; u1 = g4.y * inv; u2 = g4.z * inv; u3 = g4.w * inv;
            *(float4*)(y_lds + 4 * tid) = make_float4(u0, u1, u2, u3);
        }
    }
    partials(false);   // Q*u for Rayleigh quotient

    float step2 = 0.f, t = 1.0f, tau_ws = 0.0f, tau_pv = 0.0f, rm = 0.0f;
    float wa = 0.f, wb = 0.f, wc = 0.f, wd = 0.f;
    float ya = 0.f, yb = 0.f, yc = 0.f, yd = 0.f;
    if (tid < 64) {
        float4 g4 = reduceg();
        float lm = wsum(u0*g4.x + u1*g4.y + u2*g4.z + u3*g4.w);
        float step = 1.0f / (2.0f * lm + 1e-12f);
        step2 = 2.0f * step;
        wa = wb = wc = wd = 1.0f / 256.0f;    // project(uniform) = uniform (tau=0)
        ya = yb = yc = yd = 1.0f / 256.0f;
        *(float4*)(y_lds + 4 * tid) = make_float4(ya, yb, yc, yd);
    }
    if (tid == 0) done_flag = 0;               // ordered by next B1

    // ---------------- Phase 3: FISTA ----------------
    for (int itn = 0; itn < 300; ++itn) {
        if (partials(true)) break;             // frozen-w early exit (uniform)
        if (tid < 64) {
            float4 g4 = reduceg();
            float v0 = ya - step2 * g4.x;
            float v1 = yb - step2 * g4.y;
            float v2 = yc - step2 * g4.z;
            float v3 = yd - step2 * g4.w;

            // constant safeguard bracket: |v|inf <= ~1.5 so s(-2)>1>s(2) always
            float lo = -2.0f, hi = 2.0f;
            // extrapolated warm start (tau moves smoothly across FISTA iters)
            float tau = fminf(fmaxf(tau_ws + (tau_ws - tau_pv), lo), hi);

            float s = 0.f, cnt = 1.f, sm1 = 0.f;
            bool have = false;
            for (int ni = 0; ni < 10; ++ni) {
                float z0 = v0 - tau, z1 = v1 - tau, z2 = v2 - tau, z3 = v3 - tau;
                float c0 = fminf(fmaxf(z0, -CAPW), CAPW);
                float c1 = fminf(fmaxf(z1, -CAPW), CAPW);
                float c2 = fminf(fmaxf(z2, -CAPW), CAPW);
                float c3 = fminf(fmaxf(z3, -CAPW), CAPW);
                s   = wsum(c0 + c1 + c2 + c3);
                cnt = wsum((fabsf(z0) < CAPW ? 1.f : 0.f) +
                           (fabsf(z1) < CAPW ? 1.f : 0.f) +
                           (fabsf(z2) < CAPW ? 1.f : 0.f) +
                           (fabsf(z3) < CAPW ? 1.f : 0.f));
                sm1 = s - 1.0f;
                if (fabsf(sm1) <= 5e-5f) { have = true; break; }   // wave-uniform
                if (sm1 > 0.0f) lo = tau; else hi = tau;
                float tn2 = tau + sm1 / fmaxf(cnt, 1.0f);   // Newton: s' = -n_int
                if (!(tn2 > lo && tn2 < hi)) tn2 = 0.5f * (lo + hi);
                tau = tn2;
            }
            if (!have) {   // bound-exit: re-eval (s,cnt) at final tau
                float z0 = v0 - tau, z1 = v1 - tau, z2 = v2 - tau, z3 = v3 - tau;
                float c0 = fminf(fmaxf(z0, -CAPW), CAPW);
                float c1 = fminf(fmaxf(z1, -CAPW), CAPW);
                float c2 = fminf(fmaxf(z2, -CAPW), CAPW);
                float c3 = fminf(fmaxf(z3, -CAPW), CAPW);
                s   = wsum(c0 + c1 + c2 + c3);
                cnt = wsum((fabsf(z0) < CAPW ? 1.f : 0.f) +
                           (fabsf(z1) < CAPW ? 1.f : 0.f) +
                           (fabsf(z2) < CAPW ? 1.f : 0.f) +
                           (fabsf(z3) < CAPW ? 1.f : 0.f));
                sm1 = s - 1.0f;
            }
            // exact active-set tau == one Newton step from converged point
            float tauf = tau + sm1 / fmaxf(cnt, 1.0f);
            tau_pv = tau_ws;
            tau_ws = tauf;
            float w0n = fminf(fmaxf(v0 - tauf, -CAPW), CAPW);
            float w1n = fminf(fmaxf(v1 - tauf, -CAPW), CAPW);
            float w2n = fminf(fmaxf(v2 - tauf, -CAPW), CAPW);
            float w3n = fminf(fmaxf(v3 - tauf, -CAPW), CAPW);

            float tn = 0.5f * (1.0f + sqrtf(1.0f + 4.0f * t * t));
            float beta = (t - 1.0f) / tn;
            float y0n = w0n + beta * (w0n - wa);
            float y1n = w1n + beta * (w1n - wb);
            float y2n = w2n + beta * (w2n - wc);
            float y3n = w3n + beta * (w3n - wd);

            // frozen-w detection (8-iter window, fp32 fixed point only)
            float dm = fmaxf(fmaxf(fabsf(w0n - wa), fabsf(w1n - wb)),
                             fmaxf(fabsf(w2n - wc), fabsf(w3n - wd)));
            rm = fmaxf(rm, dm);
            if ((itn & 7) == 7) {
                float rmax = wmax(rm);
                if (rmax < 1e-10f && tid == 0) done_flag = 1;
                rm = 0.0f;
            }

            wa = w0n; wb = w1n; wc = w2n; wd = w3n;
            ya = y0n; yb = y1n; yc = y2n; yd = y3n;
            t = tn;
            *(float4*)(y_lds + 4 * tid) = make_float4(ya, yb, yc, yd);
        }
    }

    if (tid < 64) {
        *(float4*)(out + b * 256 + 4 * tid) = make_float4(wa, wb, wc, wd);
    }
}

extern "C" void kernel_launch(void* const* d_in, const int* in_sizes, int n_in,
                              void* d_out, int out_size, void* d_ws, size_t ws_size,
                              hipStream_t stream) {
    (void)in_sizes; (void)n_in; (void)d_ws; (void)ws_size; (void)out_size;
    const float* A = (const float*)d_in[0];
    float* out = (float*)d_out;
    hipLaunchKernelGGL(markowitz_fista, dim3(512), dim3(512), 0, stream, A, out);
}